// Round 16
// baseline (245.161 us; speedup 1.0000x reference)
//
#include <hip/hip_runtime.h>
#include <math.h>

#define N_NODES 50000
#define N_EDGES 800000
#define F_IN    128
#define F_OUT   64
#define ALPHA   0.2f

#define NBKT    392                // buckets of 128 nodes: 392*128 = 50176
#define BNODES  128                // nodes per bucket (src>>7)
#define EBLK    4096               // edges per binscatter block -> 196 blocks
#define CHUNK   2048               // gather LDS chunk (edges)

// ---------------------------------------------------------------------------
// K1 (R10 design, measured good): classic LDS-tiled GEMM.
// ---------------------------------------------------------------------------
__global__ __launch_bounds__(256) void k_gemm_scores(
    const float* __restrict__ in, const float* __restrict__ W,
    const float* __restrict__ a, float* __restrict__ h,
    float* __restrict__ ssrc, float* __restrict__ sdst) {
  __shared__ float Ws[F_IN][F_OUT];     // 32 KB   [k][c]
  __shared__ float As[64][68];          // 17 KB   [k][r], +4 pad
  __shared__ float al[2 * F_OUT];

  const int tid  = threadIdx.x;
  const int row0 = blockIdx.x * 64;

  {
    const float4* Wg = reinterpret_cast<const float4*>(W);
    float4* Wl = reinterpret_cast<float4*>(&Ws[0][0]);
    #pragma unroll
    for (int i = 0; i < 8; ++i) Wl[tid + i * 256] = Wg[tid + i * 256];
  }
  if (tid < 2 * F_OUT) al[tid] = a[tid];

  const int rg = tid >> 4;
  const int cg = tid & 15;
  const int sr = tid >> 2;
  const int sq = tid & 3;
  int grow = row0 + sr; if (grow >= N_NODES) grow = N_NODES - 1;

  float acc[4][4] = {{0.f}};

  for (int kc = 0; kc < 2; ++kc) {
    if (kc) __syncthreads();
    #pragma unroll
    for (int i = 0; i < 4; ++i) {
      const int slot = sq + 4 * i;
      const float4 v = *reinterpret_cast<const float4*>(
          in + (size_t)grow * F_IN + kc * 64 + slot * 4);
      As[slot * 4 + 0][sr] = v.x;
      As[slot * 4 + 1][sr] = v.y;
      As[slot * 4 + 2][sr] = v.z;
      As[slot * 4 + 3][sr] = v.w;
    }
    __syncthreads();

    #pragma unroll 8
    for (int kk = 0; kk < 64; ++kk) {
      const float4 av = *reinterpret_cast<const float4*>(&As[kk][rg * 4]);
      const float4 bv = *reinterpret_cast<const float4*>(&Ws[kc * 64 + kk][cg * 4]);
      acc[0][0] = fmaf(av.x, bv.x, acc[0][0]);
      acc[0][1] = fmaf(av.x, bv.y, acc[0][1]);
      acc[0][2] = fmaf(av.x, bv.z, acc[0][2]);
      acc[0][3] = fmaf(av.x, bv.w, acc[0][3]);
      acc[1][0] = fmaf(av.y, bv.x, acc[1][0]);
      acc[1][1] = fmaf(av.y, bv.y, acc[1][1]);
      acc[1][2] = fmaf(av.y, bv.z, acc[1][2]);
      acc[1][3] = fmaf(av.y, bv.w, acc[1][3]);
      acc[2][0] = fmaf(av.z, bv.x, acc[2][0]);
      acc[2][1] = fmaf(av.z, bv.y, acc[2][1]);
      acc[2][2] = fmaf(av.z, bv.z, acc[2][2]);
      acc[2][3] = fmaf(av.z, bv.w, acc[2][3]);
      acc[3][0] = fmaf(av.w, bv.x, acc[3][0]);
      acc[3][1] = fmaf(av.w, bv.y, acc[3][1]);
      acc[3][2] = fmaf(av.w, bv.z, acc[3][2]);
      acc[3][3] = fmaf(av.w, bv.w, acc[3][3]);
    }
  }

  #pragma unroll
  for (int i = 0; i < 4; ++i) {
    const int row = row0 + rg * 4 + i;
    if (row < N_NODES) {
      float4 hv = make_float4(acc[i][0], acc[i][1], acc[i][2], acc[i][3]);
      *reinterpret_cast<float4*>(h + (size_t)row * F_OUT + cg * 4) = hv;
    }
  }

  float ssr[4], sdr[4];
  #pragma unroll
  for (int i = 0; i < 4; ++i) {
    ssr[i] = acc[i][0] * al[cg * 4 + 0] + acc[i][1] * al[cg * 4 + 1]
           + acc[i][2] * al[cg * 4 + 2] + acc[i][3] * al[cg * 4 + 3];
    sdr[i] = acc[i][0] * al[F_OUT + cg * 4 + 0] + acc[i][1] * al[F_OUT + cg * 4 + 1]
           + acc[i][2] * al[F_OUT + cg * 4 + 2] + acc[i][3] * al[F_OUT + cg * 4 + 3];
  }
  #pragma unroll
  for (int m = 1; m < 16; m <<= 1) {
    #pragma unroll
    for (int i = 0; i < 4; ++i) {
      ssr[i] += __shfl_xor(ssr[i], m);
      sdr[i] += __shfl_xor(sdr[i], m);
    }
  }
  if (cg == 0) {
    #pragma unroll
    for (int i = 0; i < 4; ++i) {
      const int row = row0 + rg * 4 + i;
      if (row < N_NODES) { ssrc[row] = ssr[i]; sdst[row] = sdr[i]; }
    }
  }
}

// ---------------------------------------------------------------------------
// Bucket histogram (bucket = src>>7). LDS-preaggregated -> 392 global
// atomics per block instead of 256.
// ---------------------------------------------------------------------------
__global__ __launch_bounds__(256) void k_bhist(const int* __restrict__ src,
                                               int* __restrict__ bcnt) {
  __shared__ int lh[NBKT];
  for (int i = threadIdx.x; i < NBKT; i += 256) lh[i] = 0;
  __syncthreads();
  const int e = blockIdx.x * 256 + threadIdx.x;   // grid exact: 800000
  atomicAdd(&lh[src[e] >> 7], 1);
  __syncthreads();
  for (int i = threadIdx.x; i < NBKT; i += 256)
    if (lh[i]) atomicAdd(&bcnt[i], lh[i]);
}

// exclusive scan of 392 bucket counts (padded to 512; bcnt ours, zeroed).
// bbase[b>=NBKT] = total, so bbase[b+1] is valid for b = NBKT-1.
__global__ __launch_bounds__(512) void k_bscan(const int* __restrict__ bcnt,
                                               int* __restrict__ bbase) {
  __shared__ int scn[512];
  const int tid = threadIdx.x;
  const int v = (tid < NBKT) ? bcnt[tid] : 0;
  scn[tid] = v;
  __syncthreads();
  #pragma unroll
  for (int off = 1; off < 512; off <<= 1) {
    int t = (tid >= off) ? scn[tid - off] : 0;
    __syncthreads();
    scn[tid] += t;
    __syncthreads();
  }
  bbase[tid] = scn[tid] - v;
}

// ---------------------------------------------------------------------------
// R15 binscatter: LDS counting-sort per 4096-edge block, then COALESCED
// writeout. Diagnosis R12/R14/R15: random 8B stores stay ~41-47MB
// WRITE_SIZE under every cache-locality scheme -> L2 is effectively
// no-write-allocate for scattered stores; only lane-contiguous stores fix
// it. Here: sort block's edges by bucket in LDS, reserve one global
// segment per (block,bucket) via a single atomic, write sorted records
// with consecutive lanes -> consecutive addresses (~21-edge/167B runs).
// Record packing: w0 = d | (s&127)<<16 | (s>>7)<<23  (16+7+9 = 32 bits).
// ---------------------------------------------------------------------------
__global__ __launch_bounds__(512) void k_binscatter(
    const int* __restrict__ src, const int* __restrict__ dst,
    const float* __restrict__ adj,
    const float* __restrict__ ssrc, const float* __restrict__ sdst,
    const int* __restrict__ bbase, int* __restrict__ bcursor,
    int2* __restrict__ pairs) {
  __shared__ int lh[512], lofs[512], lcur[512], gbase[512], scn[512];
  __shared__ int2 led[EBLK];                     // 32 KB
  const int tid = threadIdx.x;
  const int e0  = blockIdx.x * EBLK;
  const int cnt = min(EBLK, N_EDGES - e0);

  lh[tid] = 0; lcur[tid] = 0;
  __syncthreads();

  int2 rec[8]; int rbkt[8];
  #pragma unroll
  for (int k = 0; k < 8; ++k) {
    const int i = tid + k * 512;
    rbkt[k] = -1;
    if (i < cnt) {
      const int e = e0 + i;
      const int s = src[e], d = dst[e];
      const float sc = ssrc[s] + sdst[d];
      const float lr = sc > 0.f ? sc : ALPHA * sc;
      const float ee = expf(-lr) * adj[e];
      const int bkt = s >> 7;
      const unsigned w0 = (unsigned)d | ((unsigned)(s & 127) << 16)
                        | ((unsigned)bkt << 23);
      rec[k]  = make_int2((int)w0, __float_as_int(ee));
      rbkt[k] = bkt;
      atomicAdd(&lh[bkt], 1);
    }
  }
  __syncthreads();
  scn[tid] = lh[tid];
  __syncthreads();
  #pragma unroll
  for (int off = 1; off < 512; off <<= 1) {
    int t = (tid >= off) ? scn[tid - off] : 0;
    __syncthreads();
    scn[tid] += t;
    __syncthreads();
  }
  lofs[tid] = scn[tid] - lh[tid];
  __syncthreads();
  #pragma unroll
  for (int k = 0; k < 8; ++k)
    if (rbkt[k] >= 0)
      led[lofs[rbkt[k]] + atomicAdd(&lcur[rbkt[k]], 1)] = rec[k];
  if (tid < NBKT && lh[tid] > 0)                  // reserve global segment
    gbase[tid] = bbase[tid] + atomicAdd(&bcursor[tid], lh[tid]);
  __syncthreads();
  for (int i = tid; i < cnt; i += 512) {          // coalesced writeout
    const int2 r  = led[i];
    const int bkt = ((unsigned)r.x) >> 23;
    pairs[gbase[bkt] + (i - lofs[bkt])] = r;
  }
}

// ---------------------------------------------------------------------------
// Gather per bucket: one block = 128 nodes, 8 waves. Stage <=2048-edge
// chunks in LDS, build exact per-node CSR in LDS (random writes free
// there), then wave-per-node gather: 256B coalesced h-row reads,
// 2-unrolled for MLP; fused divide + ELU. deg==0 -> 0/0 NaN matches ref.
// ---------------------------------------------------------------------------
__global__ __launch_bounds__(512) void k_gather_b(
    const int2* __restrict__ pairs, const int* __restrict__ bbase,
    const float* __restrict__ h, float* __restrict__ out) {
  __shared__ int2 sed[CHUNK], sed2[CHUNK];        // 16 KB + 16 KB
  __shared__ int lh[BNODES], lofs[BNODES], lcur[BNODES], scn[BNODES];
  const int tid  = threadIdx.x;
  const int wav  = tid >> 6, lane = tid & 63;
  const int b    = blockIdx.x;
  const int e0   = bbase[b], e1 = bbase[b + 1];

  float acc[16], rs[16];
  #pragma unroll
  for (int i = 0; i < 16; ++i) { acc[i] = 0.f; rs[i] = 0.f; }

  for (int cs = e0; cs < e1; cs += CHUNK) {
    const int cnt = min(CHUNK, e1 - cs);
    __syncthreads();                              // protect prev-iter LDS
    if (tid < BNODES) { lh[tid] = 0; lcur[tid] = 0; }
    __syncthreads();
    for (int i = tid; i < cnt; i += 512) {
      const int2 r = pairs[cs + i];
      sed[i] = r;
      atomicAdd(&lh[(r.x >> 16) & 127], 1);
    }
    __syncthreads();
    if (tid < BNODES) scn[tid] = lh[tid];
    __syncthreads();
    #pragma unroll
    for (int off = 1; off < BNODES; off <<= 1) {
      int t = 0;
      if (tid < BNODES && tid >= off) t = scn[tid - off];
      __syncthreads();
      if (tid < BNODES) scn[tid] += t;
      __syncthreads();
    }
    if (tid < BNODES) lofs[tid] = scn[tid] - lh[tid];
    __syncthreads();
    for (int i = tid; i < cnt; i += 512) {
      const int2 r = sed[i];
      const int n  = (r.x >> 16) & 127;
      sed2[lofs[n] + atomicAdd(&lcur[n], 1)] = r;
    }
    __syncthreads();
    for (int i = 0; i < 16; ++i) {                // wave's 16 nodes
      const int nl = wav * 16 + i;
      const int js = lofs[nl], je = js + lh[nl];
      int j = js;
      for (; j + 1 < je; j += 2) {
        const int2 r0 = sed2[j], r1 = sed2[j + 1];
        const float h0 = h[(size_t)(r0.x & 0xFFFF) * F_OUT + lane];
        const float h1 = h[(size_t)(r1.x & 0xFFFF) * F_OUT + lane];
        const float f0 = __int_as_float(r0.y), f1 = __int_as_float(r1.y);
        acc[i] += f0 * h0; rs[i] += f0;
        acc[i] += f1 * h1; rs[i] += f1;
      }
      if (j < je) {
        const int2 r = sed2[j];
        const float f = __int_as_float(r.y);
        acc[i] += f * h[(size_t)(r.x & 0xFFFF) * F_OUT + lane];
        rs[i]  += f;
      }
    }
  }

  #pragma unroll
  for (int i = 0; i < 16; ++i) {
    const int n = b * BNODES + wav * 16 + i;
    if (n < N_NODES) {
      float v = acc[i] / rs[i];
      v = v > 0.f ? v : expm1f(v);
      out[(size_t)n * F_OUT + lane] = v;
    }
  }
}

extern "C" void kernel_launch(void* const* d_in, const int* in_sizes, int n_in,
                              void* d_out, int out_size, void* d_ws, size_t ws_size,
                              hipStream_t stream) {
  const float* input = (const float*)d_in[0];
  const float* W     = (const float*)d_in[1];
  const float* a     = (const float*)d_in[2];
  const float* adj   = (const float*)d_in[3];
  const int*   ei    = (const int*)d_in[4];
  const int*   src   = ei;
  const int*   dst   = ei + N_EDGES;
  float* out = (float*)d_out;

  // ---- workspace layout (all regions 16B-aligned) ----
  float* h      = (float*)d_ws;                      // 3.2M floats (12.8 MB)
  float* ssrc   = h + (size_t)N_NODES * F_OUT;       // 50000
  float* sdst   = ssrc + N_NODES;                    // 50000
  int*   bcnt    = (int*)(sdst + N_NODES);           // 512 (zeroed)
  int*   bcursor = bcnt + 512;                       // 512 (zeroed)
  int*   bbase   = bcursor + 512;                    // 512
  int2*  pairs   = (int2*)(bbase + 512);             // 800000 int2 (6.4 MB)

  hipMemsetAsync(bcnt, 0, 1024 * sizeof(int), stream);  // bcnt + bcursor

  k_bhist      <<<N_EDGES / 256, 256, 0, stream>>>(src, bcnt);
  k_bscan      <<<1, 512, 0, stream>>>(bcnt, bbase);
  k_gemm_scores<<<(N_NODES + 63) / 64, 256, 0, stream>>>(input, W, a, h, ssrc, sdst);
  k_binscatter <<<(N_EDGES + EBLK - 1) / EBLK, 512, 0, stream>>>(
      src, dst, adj, ssrc, sdst, bbase, bcursor, pairs);
  k_gather_b   <<<NBKT, 512, 0, stream>>>(pairs, bbase, h, out);
}